// Round 1
// baseline (1475.182 us; speedup 1.0000x reference)
//
#include <hip/hip_runtime.h>

#define TPB 256

// ---------------- degree counting ----------------
__global__ void deg_kernel(const int* __restrict__ src, const int* __restrict__ dst,
                           int* __restrict__ dout, int* __restrict__ din, int E) {
    int i = blockIdx.x * TPB + threadIdx.x;
    if (i < E) {
        atomicAdd(&dout[src[i]], 1);
        atomicAdd(&din[dst[i]], 1);
    }
}

__global__ void scale_kernel(const int* __restrict__ deg, float* __restrict__ scl, int n) {
    int i = blockIdx.x * TPB + threadIdx.x;
    if (i < n) {
        int d = deg[i];
        scl[i] = rsqrtf((float)(d > 1 ? d : 1));
    }
}

// ---------------- GEMM 1: [N,128] @ [128,64] ----------------
__global__ void gemm1_kernel(const float* __restrict__ x, const float* __restrict__ W,
                             float* __restrict__ Y, int N) {
    __shared__ float ws[128 * 64];   // 32 KB
    __shared__ float xs[16 * 128];   // 8 KB
    int tid = threadIdx.x;
    for (int i = tid; i < 128 * 64; i += TPB) ws[i] = W[i];
    int row0 = blockIdx.x * 16;
    for (int i = tid; i < 16 * 128; i += TPB) {
        int r = row0 + (i >> 7);
        xs[i] = (r < N) ? x[(size_t)r * 128 + (i & 127)] : 0.f;
    }
    __syncthreads();
    int c  = tid & 63;
    int r0 = tid >> 6;           // 0..3
    for (int rr = 0; rr < 4; rr++) {
        int r = r0 + rr * 4;     // 0..15
        float acc = 0.f;
        #pragma unroll
        for (int k = 0; k < 128; k++) acc += xs[r * 128 + k] * ws[k * 64 + c];
        int grow = row0 + r;
        if (grow < N) Y[(size_t)grow * 64 + c] = acc;
    }
}

// ---------------- GEMM 2: [N,64] @ [64,32] ----------------
__global__ void gemm2_kernel(const float* __restrict__ H, const float* __restrict__ W,
                             float* __restrict__ Y, int N) {
    __shared__ float ws[64 * 32];    // 8 KB
    __shared__ float xs[32 * 64];    // 8 KB
    int tid = threadIdx.x;
    for (int i = tid; i < 64 * 32; i += TPB) ws[i] = W[i];
    int row0 = blockIdx.x * 32;
    for (int i = tid; i < 32 * 64; i += TPB) {
        int r = row0 + (i >> 6);
        xs[i] = (r < N) ? H[(size_t)r * 64 + (i & 63)] : 0.f;
    }
    __syncthreads();
    int c  = tid & 31;
    int r0 = tid >> 5;           // 0..7
    for (int rr = 0; rr < 4; rr++) {
        int r = r0 + rr * 8;     // 0..31
        float acc = 0.f;
        #pragma unroll
        for (int k = 0; k < 64; k++) acc += xs[r * 64 + k] * ws[k * 32 + c];
        int grow = row0 + r;
        if (grow < N) Y[(size_t)grow * 32 + c] = acc;
    }
}

// ---------------- edge aggregation: AGG[dst] += H[src] * s_out[src] ----------------
template<int F>
__global__ void agg_kernel(const int* __restrict__ src, const int* __restrict__ dst,
                           const float* __restrict__ sout,
                           const float* __restrict__ H, float* __restrict__ AGG, int E) {
    long long gid = (long long)blockIdx.x * TPB + threadIdx.x;
    int e = (int)(gid / F);
    int f = (int)(gid % F);
    if (e < E) {
        int s = src[e];
        int d = dst[e];
        float v = H[(size_t)s * F + f] * sout[s];
        atomicAdd(&AGG[(size_t)d * F + f], v);
    }
}

// ---------------- bias + relu (layer 1 epilogue, in place) ----------------
__global__ void bias_relu_kernel(float* __restrict__ A, const float* __restrict__ sin,
                                 const float* __restrict__ b, int total) {
    int i = blockIdx.x * TPB + threadIdx.x;
    if (i < total) {
        int row = i >> 6;
        float v = A[i] * sin[row] + b[i & 63];
        A[i] = v > 0.f ? v : 0.f;
    }
}

// ---------------- final epilogue: out (+)= 0.5*(A2*s_in + b2) ----------------
__global__ void out_kernel(const float* __restrict__ A2, const float* __restrict__ sin,
                           const float* __restrict__ b, float* __restrict__ out,
                           int total, int first) {
    int i = blockIdx.x * TPB + threadIdx.x;
    if (i < total) {
        int row = i >> 5;
        float v = 0.5f * (A2[i] * sin[row] + b[i & 31]);
        out[i] = first ? v : out[i] + v;
    }
}

extern "C" void kernel_launch(void* const* d_in, const int* in_sizes, int n_in,
                              void* d_out, int out_size, void* d_ws, size_t ws_size,
                              hipStream_t stream) {
    const float* x    = (const float*)d_in[0];
    const int* srcs[2] = {(const int*)d_in[1], (const int*)d_in[3]};
    const int* dsts[2] = {(const int*)d_in[2], (const int*)d_in[4]};
    const float* W1   = (const float*)d_in[5];
    const float* b1   = (const float*)d_in[6];
    const float* W2   = (const float*)d_in[7];
    const float* b2   = (const float*)d_in[8];
    float* out        = (float*)d_out;

    const int N = in_sizes[0] / 128;   // 100000
    const int E = in_sizes[1];         // 1600000

    // workspace layout (floats): Y1[N*64] | AGG[N*64] | H2P[N*32] | AGG2[N*32] | DEG[4N int] | SCL[4N]
    float* ws   = (float*)d_ws;
    float* Y1   = ws;
    float* AGG  = Y1  + (size_t)N * 64;
    float* H2P  = AGG + (size_t)N * 64;
    float* AGG2 = H2P + (size_t)N * 32;
    int*   DEG  = (int*)(AGG2 + (size_t)N * 32);
    float* SCL  = (float*)(DEG + (size_t)4 * N);

    hipMemsetAsync(DEG, 0, sizeof(int) * (size_t)4 * N, stream);
    int eb = (E + TPB - 1) / TPB;
    deg_kernel<<<eb, TPB, 0, stream>>>(srcs[0], dsts[0], DEG,         DEG + N,     E);
    deg_kernel<<<eb, TPB, 0, stream>>>(srcs[1], dsts[1], DEG + 2 * N, DEG + 3 * N, E);
    scale_kernel<<<(4 * N + TPB - 1) / TPB, TPB, 0, stream>>>(DEG, SCL, 4 * N);

    gemm1_kernel<<<(N + 15) / 16, TPB, 0, stream>>>(x, W1, Y1, N);

    for (int g = 0; g < 2; g++) {
        const float* so = SCL + (size_t)(2 * g) * N;      // rsqrt(deg_out)
        const float* si = SCL + (size_t)(2 * g + 1) * N;  // rsqrt(deg_in)

        hipMemsetAsync(AGG, 0, sizeof(float) * (size_t)N * 64, stream);
        long long t1 = (long long)E * 64;
        agg_kernel<64><<<(int)((t1 + TPB - 1) / TPB), TPB, 0, stream>>>(
            srcs[g], dsts[g], so, Y1, AGG, E);
        bias_relu_kernel<<<(N * 64 + TPB - 1) / TPB, TPB, 0, stream>>>(AGG, si, b1, N * 64);

        gemm2_kernel<<<(N + 31) / 32, TPB, 0, stream>>>(AGG, W2, H2P, N);

        hipMemsetAsync(AGG2, 0, sizeof(float) * (size_t)N * 32, stream);
        long long t2 = (long long)E * 32;
        agg_kernel<32><<<(int)((t2 + TPB - 1) / TPB), TPB, 0, stream>>>(
            srcs[g], dsts[g], so, H2P, AGG2, E);
        out_kernel<<<(N * 32 + TPB - 1) / TPB, TPB, 0, stream>>>(AGG2, si, b2, out, N * 32, g == 0);
    }
}

// Round 2
// 953.077 us; speedup vs baseline: 1.5478x; 1.5478x over previous
//
#include <hip/hip_runtime.h>

#define TPB 256

// ---------------- degree counting ----------------
__global__ void deg_kernel(const int* __restrict__ src, const int* __restrict__ dst,
                           int* __restrict__ dout, int* __restrict__ din, int E) {
    int i = blockIdx.x * TPB + threadIdx.x;
    if (i < E) {
        atomicAdd(&dout[src[i]], 1);
        atomicAdd(&din[dst[i]], 1);
    }
}

__global__ void scale_kernel(const int* __restrict__ deg, float* __restrict__ scl, int n) {
    int i = blockIdx.x * TPB + threadIdx.x;
    if (i < n) {
        int d = deg[i];
        scl[i] = rsqrtf((float)(d > 1 ? d : 1));
    }
}

// ---------------- scan (3-kernel exclusive prefix sum over N degrees) ----------------
// each block covers 1024 elements (256 threads x 4)
__global__ void scanA_kernel(const int* __restrict__ deg, int* __restrict__ bsum, int n) {
    __shared__ int lds[TPB];
    int t = threadIdx.x;
    int base = blockIdx.x * 1024;
    int s = 0;
    #pragma unroll
    for (int j = 0; j < 4; j++) {
        int idx = base + t * 4 + j;
        if (idx < n) s += deg[idx];
    }
    lds[t] = s;
    __syncthreads();
    for (int off = TPB / 2; off > 0; off >>= 1) {
        if (t < off) lds[t] += lds[t + off];
        __syncthreads();
    }
    if (t == 0) bsum[blockIdx.x] = lds[0];
}

__global__ void scanB_kernel(int* __restrict__ bsum, int nb) {
    if (threadIdx.x == 0 && blockIdx.x == 0) {
        int run = 0;
        for (int i = 0; i < nb; i++) { int v = bsum[i]; bsum[i] = run; run += v; }
    }
}

__global__ void scanC_kernel(const int* __restrict__ deg, const int* __restrict__ bsum,
                             int* __restrict__ rowptr, int n) {
    __shared__ int lds[TPB];
    int t = threadIdx.x;
    int base = blockIdx.x * 1024;
    int idx0 = base + t * 4;
    int d[4];
    #pragma unroll
    for (int j = 0; j < 4; j++) d[j] = (idx0 + j < n) ? deg[idx0 + j] : 0;
    int p1 = d[0], p2 = p1 + d[1], p3 = p2 + d[2], ts = p3 + d[3];
    lds[t] = ts;
    __syncthreads();
    for (int off = 1; off < TPB; off <<= 1) {
        int v = (t >= off) ? lds[t - off] : 0;
        __syncthreads();
        lds[t] += v;
        __syncthreads();
    }
    int excl = lds[t] - ts + bsum[blockIdx.x];
    if (idx0 < n)     rowptr[idx0]     = excl;
    if (idx0 + 1 < n) rowptr[idx0 + 1] = excl + p1;
    if (idx0 + 2 < n) rowptr[idx0 + 2] = excl + p2;
    if (idx0 + 3 < n) rowptr[idx0 + 3] = excl + p3;
}

// ---------------- counting-sort scatter: edges grouped by dst ----------------
__global__ void scatter_kernel(const int* __restrict__ src, const int* __restrict__ dst,
                               const int* __restrict__ rowptr, int* __restrict__ cnt,
                               int* __restrict__ esrc, int E) {
    int e = blockIdx.x * TPB + threadIdx.x;
    if (e < E) {
        int d = dst[e];
        int pos = rowptr[d] + atomicAdd(&cnt[d], 1);
        esrc[pos] = src[e];
    }
}

// ---------------- GEMM 1: [N,128] @ [128,64] ----------------
__global__ void gemm1_kernel(const float* __restrict__ x, const float* __restrict__ W,
                             float* __restrict__ Y, int N) {
    __shared__ float ws[128 * 64];   // 32 KB
    __shared__ float xs[16 * 128];   // 8 KB
    int tid = threadIdx.x;
    for (int i = tid; i < 128 * 64; i += TPB) ws[i] = W[i];
    int row0 = blockIdx.x * 16;
    for (int i = tid; i < 16 * 128; i += TPB) {
        int r = row0 + (i >> 7);
        xs[i] = (r < N) ? x[(size_t)r * 128 + (i & 127)] : 0.f;
    }
    __syncthreads();
    int c  = tid & 63;
    int r0 = tid >> 6;           // 0..3
    for (int rr = 0; rr < 4; rr++) {
        int r = r0 + rr * 4;     // 0..15
        float acc = 0.f;
        #pragma unroll
        for (int k = 0; k < 128; k++) acc += xs[r * 128 + k] * ws[k * 64 + c];
        int grow = row0 + r;
        if (grow < N) Y[(size_t)grow * 64 + c] = acc;
    }
}

// ---------------- GEMM 2 (in place): H[:, 0:32] = H[:, 0:64] @ W2 ----------------
__global__ void gemm2_kernel(float* __restrict__ H, const float* __restrict__ W, int N) {
    __shared__ float ws[64 * 32];    // 8 KB
    __shared__ float xs[32 * 64];    // 8 KB
    int tid = threadIdx.x;
    for (int i = tid; i < 64 * 32; i += TPB) ws[i] = W[i];
    int row0 = blockIdx.x * 32;
    for (int i = tid; i < 32 * 64; i += TPB) {
        int r = row0 + (i >> 6);
        xs[i] = (r < N) ? H[(size_t)r * 64 + (i & 63)] : 0.f;
    }
    __syncthreads();
    int c  = tid & 31;
    int r0 = tid >> 5;           // 0..7
    for (int rr = 0; rr < 4; rr++) {
        int r = r0 + rr * 8;     // 0..31
        float acc = 0.f;
        #pragma unroll
        for (int k = 0; k < 64; k++) acc += xs[r * 64 + k] * ws[k * 32 + c];
        int grow = row0 + r;
        if (grow < N) H[(size_t)grow * 64 + c] = acc;   // in-place, cols 0..31
    }
}

// ---------------- layer-1 gather aggregate + fused bias/relu/s_in ----------------
// one wave per node, lane = feature (64)
__global__ void agg1_kernel(const int* __restrict__ esrc, const int* __restrict__ rowptr,
                            const int* __restrict__ deg,
                            const float* __restrict__ sout, const float* __restrict__ sin,
                            const float* __restrict__ b1,
                            const float* __restrict__ Y1, float* __restrict__ H1, int N) {
    int node = blockIdx.x * 4 + (threadIdx.x >> 6);
    int f = threadIdx.x & 63;
    if (node >= N) return;
    int start = rowptr[node];
    int dn = deg[node];
    float acc = 0.f;
    int i = 0;
    for (; i + 2 <= dn; i += 2) {
        int s0 = esrc[start + i];
        int s1 = esrc[start + i + 1];
        float w0 = sout[s0];
        float w1 = sout[s1];
        acc += Y1[(size_t)s0 * 64 + f] * w0;
        acc += Y1[(size_t)s1 * 64 + f] * w1;
    }
    if (i < dn) {
        int s0 = esrc[start + i];
        acc += Y1[(size_t)s0 * 64 + f] * sout[s0];
    }
    float v = acc * sin[node] + b1[f];
    H1[(size_t)node * 64 + f] = v > 0.f ? v : 0.f;
}

// ---------------- layer-2 gather aggregate + fused epilogue (mean over graphs) ----------------
// half-wave per node, lane = feature (32); H2 rows are stride-64 (in-place gemm2 output)
__global__ void agg2_kernel(const int* __restrict__ esrc, const int* __restrict__ rowptr,
                            const int* __restrict__ deg,
                            const float* __restrict__ sout, const float* __restrict__ sin,
                            const float* __restrict__ b2,
                            const float* __restrict__ H2, float* __restrict__ out,
                            int N, int first) {
    int node = blockIdx.x * 8 + (threadIdx.x >> 5);
    int f = threadIdx.x & 31;
    if (node >= N) return;
    int start = rowptr[node];
    int dn = deg[node];
    float acc = 0.f;
    int i = 0;
    for (; i + 2 <= dn; i += 2) {
        int s0 = esrc[start + i];
        int s1 = esrc[start + i + 1];
        float w0 = sout[s0];
        float w1 = sout[s1];
        acc += H2[(size_t)s0 * 64 + f] * w0;
        acc += H2[(size_t)s1 * 64 + f] * w1;
    }
    if (i < dn) {
        int s0 = esrc[start + i];
        acc += H2[(size_t)s0 * 64 + f] * sout[s0];
    }
    float v = 0.5f * (acc * sin[node] + b2[f]);
    size_t o = (size_t)node * 32 + f;
    out[o] = first ? v : out[o] + v;
}

extern "C" void kernel_launch(void* const* d_in, const int* in_sizes, int n_in,
                              void* d_out, int out_size, void* d_ws, size_t ws_size,
                              hipStream_t stream) {
    const float* x    = (const float*)d_in[0];
    const int* srcs[2] = {(const int*)d_in[1], (const int*)d_in[3]};
    const int* dsts[2] = {(const int*)d_in[2], (const int*)d_in[4]};
    const float* W1   = (const float*)d_in[5];
    const float* b1   = (const float*)d_in[6];
    const float* W2   = (const float*)d_in[7];
    const float* b2   = (const float*)d_in[8];
    float* out        = (float*)d_out;

    const int N = in_sizes[0] / 128;   // 100000
    const int E = in_sizes[1];         // 1600000
    const int NB1024 = (N + 1023) / 1024;

    // workspace layout: Y1[N*64] | H1[N*64] | DEG[4N] | SCL[4N] | ROWPTR[2N] | CNT[N] | BSUM[128] | ESRC[2E]
    float* ws     = (float*)d_ws;
    float* Y1     = ws;
    float* H1     = Y1 + (size_t)N * 64;
    int*   DEG    = (int*)(H1 + (size_t)N * 64);
    float* SCL    = (float*)(DEG + (size_t)4 * N);
    int*   ROWPTR = (int*)(SCL + (size_t)4 * N);
    int*   CNT    = ROWPTR + (size_t)2 * N;
    int*   BSUM   = CNT + N;
    int*   ESRC   = BSUM + 128;

    hipMemsetAsync(DEG, 0, sizeof(int) * (size_t)4 * N, stream);
    int eb = (E + TPB - 1) / TPB;
    deg_kernel<<<eb, TPB, 0, stream>>>(srcs[0], dsts[0], DEG,         DEG + N,     E);
    deg_kernel<<<eb, TPB, 0, stream>>>(srcs[1], dsts[1], DEG + 2 * N, DEG + 3 * N, E);
    scale_kernel<<<(4 * N + TPB - 1) / TPB, TPB, 0, stream>>>(DEG, SCL, 4 * N);

    // build CSR (edges sorted by dst) for both graphs
    for (int g = 0; g < 2; g++) {
        const int* din = DEG + (size_t)(2 * g + 1) * N;
        int* rowptr    = ROWPTR + (size_t)g * N;
        int* esrc      = ESRC + (size_t)g * E;
        scanA_kernel<<<NB1024, TPB, 0, stream>>>(din, BSUM, N);
        scanB_kernel<<<1, TPB, 0, stream>>>(BSUM, NB1024);
        scanC_kernel<<<NB1024, TPB, 0, stream>>>(din, BSUM, rowptr, N);
        hipMemsetAsync(CNT, 0, sizeof(int) * (size_t)N, stream);
        scatter_kernel<<<eb, TPB, 0, stream>>>(srcs[g], dsts[g], rowptr, CNT, esrc, E);
    }

    gemm1_kernel<<<(N + 15) / 16, TPB, 0, stream>>>(x, W1, Y1, N);

    for (int g = 0; g < 2; g++) {
        const float* so = SCL + (size_t)(2 * g) * N;      // rsqrt(deg_out)
        const float* si = SCL + (size_t)(2 * g + 1) * N;  // rsqrt(deg_in)
        const int* din  = DEG + (size_t)(2 * g + 1) * N;
        const int* rowptr = ROWPTR + (size_t)g * N;
        const int* esrc   = ESRC + (size_t)g * E;

        agg1_kernel<<<(N + 3) / 4, TPB, 0, stream>>>(esrc, rowptr, din, so, si, b1, Y1, H1, N);
        gemm2_kernel<<<(N + 31) / 32, TPB, 0, stream>>>(H1, W2, N);
        agg2_kernel<<<(N + 7) / 8, TPB, 0, stream>>>(esrc, rowptr, din, so, si, b2, H1, out, N, g == 0);
    }
}